// Round 17
// baseline (87.973 us; speedup 1.0000x reference)
//
#include <hip/hip_runtime.h>
#include <math.h>

#define N_PTS 16384
#define M_TGT 16384
#define TPN 8192
#define DUB2 4.0f
#define SCAT_BLKS 16
#define SEL_BLK 16
#define FIN0 17
#define FINAL_ROWS 128
#define FINAL_BLKS 128

__device__ __forceinline__ unsigned int mono_key(float f) {
    unsigned int u = __float_as_uint(f);
    return (u & 0x80000000u) ? ~u : (u | 0x80000000u);
}

// 33 integer offsets with dx^2+dy^2+dz^2 <= 4, grouped by d2 = 0,1,2,3,4.
__device__ const signed char NOFF[33][3] = {
    {0,0,0},
    {1,0,0},{-1,0,0},{0,1,0},{0,-1,0},{0,0,1},{0,0,-1},
    {1,1,0},{1,-1,0},{-1,1,0},{-1,-1,0},{1,0,1},{1,0,-1},{-1,0,1},{-1,0,-1},
    {0,1,1},{0,1,-1},{0,-1,1},{0,-1,-1},
    {1,1,1},{1,1,-1},{1,-1,1},{1,-1,-1},{-1,1,1},{-1,1,-1},{-1,-1,1},{-1,-1,-1},
    {2,0,0},{-2,0,0},{0,2,0},{0,-2,0},{0,0,2},{0,0,-2}
};

// K1: round-11 proven gemm (16 rows/block). Zeroes bmask + sem.
__global__ __launch_bounds__(256) void k_gemm(const float* __restrict__ fea,
        const float* __restrict__ Wup, const float* __restrict__ Wcls,
        float* __restrict__ out_pred, float* __restrict__ out_fea,
        unsigned int* __restrict__ bmask, unsigned int* __restrict__ sem) {
    __shared__ float Ws[64 * 64];
    __shared__ float fs[16 * 68];
    const int tid = threadIdx.x;
    const int r0 = blockIdx.x * 16;

    if (tid < 32) bmask[blockIdx.x * 32 + tid] = 0u;     // 1024 blocks x 32 = 32768
    else if (blockIdx.x == 0 && tid == 32) *sem = 0u;

    for (int t = tid; t < 1024; t += 256)
        ((float4*)Ws)[t] = ((const float4*)Wup)[t];
    {
        float4 v = ((const float4*)(fea + r0 * 64))[tid];
        int r = tid >> 4, c = (tid & 15) * 4;
        fs[r*68 + c + 0] = v.x; fs[r*68 + c + 1] = v.y;
        fs[r*68 + c + 2] = v.z; fs[r*68 + c + 3] = v.w;
    }
    __syncthreads();

    const int cg = tid & 15;
    const int r  = tid >> 4;
    float a0 = 0.f, a1 = 0.f, a2 = 0.f, a3 = 0.f;
    const float* fr = fs + r * 68;
    #pragma unroll
    for (int k = 0; k < 64; ++k) {
        float f = fr[k];
        float4 w = *(const float4*)&Ws[k * 64 + cg * 4];
        a0 = fmaf(f, w.x, a0); a1 = fmaf(f, w.y, a1);
        a2 = fmaf(f, w.z, a2); a3 = fmaf(f, w.w, a3);
    }
    a0 = fmaxf(a0, 0.f); a1 = fmaxf(a1, 0.f);
    a2 = fmaxf(a2, 0.f); a3 = fmaxf(a3, 0.f);
    const int row = r0 + r;
    *(float4*)&out_fea[row * 64 + cg * 4] = make_float4(a0, a1, a2, a3);

    float4 wc = *(const float4*)&Wcls[cg * 4];
    float s = a0*wc.x + a1*wc.y + a2*wc.z + a3*wc.w;
    for (int off = 1; off < 16; off <<= 1) s += __shfl_xor(s, off, 16);
    if (cg == 0) out_pred[row] = s;
}

// K2: fused. blocks 0..15 scatter -> sem++; block 16 select -> thres, sem++;
// blocks 17..144 final: spin until sem==17, then probe+epilogue.
// All cross-block data written AND read via device-scope atomics.
__global__ __launch_bounds__(1024) void k_fused(const float* __restrict__ pred,
        const int* __restrict__ coords, const int* __restrict__ tcoords,
        unsigned int* __restrict__ bmask, unsigned int* __restrict__ sem,
        unsigned int* __restrict__ thres_u,
        float* __restrict__ out_fea, float* __restrict__ out_keep,
        float* __restrict__ out_kt, float* __restrict__ out_loss) {
    __shared__ unsigned int keys[N_PTS];        // 64 KB (select only)
    __shared__ unsigned int whist[16][256];     // 16 KB
    __shared__ unsigned int hist[256];
    __shared__ unsigned int scanb[256];
    __shared__ unsigned int sh_prefix, sh_rank;
    __shared__ float kscale[FINAL_ROWS];
    const int tid = threadIdx.x;
    const int blk = blockIdx.x;

    if (blk < SCAT_BLKS) {                      // ---- scatter ----
        const int id = blk * 1024 + tid;
        int4 c = *(const int4*)&tcoords[id * 4];
        int key = ((c.x * 64 + c.y) * 64 + c.z) * 64 + c.w;
        atomicOr(&bmask[key >> 5], 1u << (key & 31));
        __threadfence();
        __syncthreads();
        if (tid == 0)
            __hip_atomic_fetch_add(sem, 1u, __ATOMIC_RELEASE, __HIP_MEMORY_SCOPE_AGENT);
        return;
    }

    if (blk == SEL_BLK) {                       // ---- select (round-11) ----
        const int w = tid >> 6;
        for (int i = tid; i < N_PTS / 4; i += 1024) {
            float4 v = ((const float4*)pred)[i];
            keys[i*4 + 0] = mono_key(v.x);
            keys[i*4 + 1] = mono_key(v.y);
            keys[i*4 + 2] = mono_key(v.z);
            keys[i*4 + 3] = mono_key(v.w);
        }
        if (tid == 0) { sh_prefix = 0u; sh_rank = TPN - 1; }
        __syncthreads();
        for (int pass = 0; pass < 4; ++pass) {
            const int shift = 24 - pass * 8;
            const unsigned int prefix = sh_prefix;
            const unsigned int rank = sh_rank;
            for (int t = tid; t < 16 * 256; t += 1024) ((unsigned int*)whist)[t] = 0u;
            __syncthreads();
            for (int i = tid; i < N_PTS; i += 1024) {
                unsigned int u = keys[i];
                bool match = (pass == 0) || ((u >> (shift + 8)) == prefix);
                if (match) atomicAdd(&whist[w][(u >> shift) & 255u], 1u);
            }
            __syncthreads();
            if (tid < 256) {
                unsigned int s = 0u;
                #pragma unroll
                for (int ww = 0; ww < 16; ++ww) s += whist[ww][tid];
                hist[tid] = s;
                scanb[tid] = s;
            }
            __syncthreads();
            for (int d = 1; d < 256; d <<= 1) {
                unsigned int v = 0u;
                if (tid < 256 && tid >= d) v = scanb[tid - d];
                __syncthreads();
                if (tid < 256) scanb[tid] += v;
                __syncthreads();
            }
            if (tid < 256) {
                unsigned int hi = scanb[tid];
                unsigned int lo = hi - hist[tid];
                if (rank >= lo && rank < hi) {
                    sh_prefix = (prefix << 8) | (unsigned int)tid;
                    sh_rank = rank - lo;
                }
            }
            __syncthreads();
        }
        if (tid == 0) {
            unsigned int u = sh_prefix;
            unsigned int tv = (u & 0x80000000u) ? (u ^ 0x80000000u) : ~u;
            __hip_atomic_store(thres_u, tv, __ATOMIC_RELAXED, __HIP_MEMORY_SCOPE_AGENT);
        }
        __threadfence();
        __syncthreads();
        if (tid == 0)
            __hip_atomic_fetch_add(sem, 1u, __ATOMIC_RELEASE, __HIP_MEMORY_SCOPE_AGENT);
        return;
    }

    // ---- final ----
    const int r0 = (blk - FIN0) * FINAL_ROWS;
    if (tid == 0) {
        while (__hip_atomic_load(sem, __ATOMIC_ACQUIRE, __HIP_MEMORY_SCOPE_AGENT)
               < (unsigned)(SCAT_BLKS + 1))
            __builtin_amdgcn_s_sleep(8);
    }
    __syncthreads();
    __threadfence();
    if (tid < FINAL_ROWS) {
        const int i = r0 + tid;
        float p = pred[i];
        float thres = __uint_as_float(
            __hip_atomic_load(thres_u, __ATOMIC_RELAXED, __HIP_MEMORY_SCOPE_AGENT));
        int4 c = *(const int4*)&coords[i * 4];
        const int b = c.x, x = c.y, y = c.z, z = c.w;
        int key0 = ((b * 64 + x) * 64 + y) * 64 + z;
        bool kt = (atomicOr(&bmask[key0 >> 5], 0u) >> (key0 & 31)) & 1u;
        float dists;
        if (kt) {
            dists = 0.f;
        } else {
            dists = 5.f;                        // sentinel > DUB2: "not found"
            int t = 1;
            #pragma unroll
            for (int g = 1; g <= 4; ++g) {
                const int gend = (g == 1) ? 7 : (g == 2) ? 19 : (g == 3) ? 27 : 33;
                bool hit = false;
                for (; t < gend; ++t) {
                    int ox = x + NOFF[t][0], oy = y + NOFF[t][1], oz = z + NOFF[t][2];
                    if (((unsigned)ox | (unsigned)oy | (unsigned)oz) < 64u) {
                        int key = ((b * 64 + ox) * 64 + oy) * 64 + oz;
                        hit |= (atomicOr(&bmask[key >> 5], 0u) >> (key & 31)) & 1u;
                    }
                }
                if (hit) { dists = (float)g; break; }
            }
        }
        bool keep0 = (p <= thres);
        bool pm = (p > DUB2), tm = (dists > DUB2);
        float loss = (pm && tm) ? p : ((!pm && tm) ? DUB2 : dists);
        bool kf = keep0 || kt;
        out_keep[i] = kf ? 1.f : 0.f;
        out_kt[i]  = kt ? 1.f : 0.f;
        out_loss[i] = loss;
        kscale[tid] = kf ? 1.f : 0.f;
    }
    __syncthreads();
    float4* fbase = (float4*)(out_fea + r0 * 64);
    #pragma unroll
    for (int q = 0; q < 2; ++q) {
        int v = tid + q * 1024;                 // 128 rows x 16 float4 = 2048
        float sc = kscale[v >> 4];
        float4 xv = fbase[v];
        xv.x *= sc; xv.y *= sc; xv.z *= sc; xv.w *= sc;
        fbase[v] = xv;
    }
}

extern "C" void kernel_launch(void* const* d_in, const int* in_sizes, int n_in,
                              void* d_out, int out_size, void* d_ws, size_t ws_size,
                              hipStream_t stream) {
    const float* fea     = (const float*)d_in[0];
    const float* Wup     = (const float*)d_in[1];
    const float* Wcls    = (const float*)d_in[2];
    const int*   coords  = (const int*)d_in[3];
    const int*   tcoords = (const int*)d_in[4];

    float* out      = (float*)d_out;
    float* out_pred = out;
    float* out_fea  = out + N_PTS;
    float* out_keep = out + N_PTS + N_PTS * 64;
    float* out_kt   = out_keep + N_PTS;
    float* out_loss = out_kt + N_PTS;

    char* ws = (char*)d_ws;
    unsigned int* sem     = (unsigned int*)ws;                 // 4 B
    unsigned int* bmask   = (unsigned int*)(ws + 64);          // 128 KB -> 131136
    unsigned int* thres_u = (unsigned int*)(ws + 131136);      // 4 B

    k_gemm <<<N_PTS / 16, 256, 0, stream>>>(fea, Wup, Wcls, out_pred, out_fea,
                                            bmask, sem);
    k_fused<<<FIN0 + FINAL_BLKS, 1024, 0, stream>>>(out_pred, coords, tcoords,
                                                    bmask, sem, thres_u,
                                                    out_fea, out_keep, out_kt, out_loss);
}

// Round 18
// 50.372 us; speedup vs baseline: 1.7465x; 1.7465x over previous
//
#include <hip/hip_runtime.h>
#include <math.h>

#define N_PTS 16384
#define M_TGT 16384
#define TPN 8192
#define DUB2 4.0f
#define BMASK_WORDS (4*64*64*64/32)

__device__ __forceinline__ unsigned int mono_key(float f) {
    unsigned int u = __float_as_uint(f);
    return (u & 0x80000000u) ? ~u : (u | 0x80000000u);
}

// 33 integer offsets with dx^2+dy^2+dz^2 <= 4, grouped by d2 = 0,1,2,3,4.
__device__ const signed char NOFF[33][3] = {
    {0,0,0},
    {1,0,0},{-1,0,0},{0,1,0},{0,-1,0},{0,0,1},{0,0,-1},
    {1,1,0},{1,-1,0},{-1,1,0},{-1,-1,0},{1,0,1},{1,0,-1},{-1,0,1},{-1,0,-1},
    {0,1,1},{0,1,-1},{0,-1,1},{0,-1,-1},
    {1,1,1},{1,1,-1},{1,-1,1},{1,-1,-1},{-1,1,1},{-1,1,-1},{-1,-1,1},{-1,-1,-1},
    {2,0,0},{-2,0,0},{0,2,0},{0,-2,0},{0,0,2},{0,0,-2}
};

// K1: round-11 proven gemm (16 rows/block). Zeroes bmask.
__global__ __launch_bounds__(256) void k_gemm(const float* __restrict__ fea,
        const float* __restrict__ Wup, const float* __restrict__ Wcls,
        float* __restrict__ out_pred, float* __restrict__ out_fea,
        unsigned int* __restrict__ bmask) {
    __shared__ float Ws[64 * 64];
    __shared__ float fs[16 * 68];
    const int tid = threadIdx.x;
    const int r0 = blockIdx.x * 16;

    if (tid < 32) bmask[blockIdx.x * 32 + tid] = 0u;

    for (int t = tid; t < 1024; t += 256)
        ((float4*)Ws)[t] = ((const float4*)Wup)[t];
    {
        float4 v = ((const float4*)(fea + r0 * 64))[tid];
        int r = tid >> 4, c = (tid & 15) * 4;
        fs[r*68 + c + 0] = v.x; fs[r*68 + c + 1] = v.y;
        fs[r*68 + c + 2] = v.z; fs[r*68 + c + 3] = v.w;
    }
    __syncthreads();

    const int cg = tid & 15;
    const int r  = tid >> 4;
    float a0 = 0.f, a1 = 0.f, a2 = 0.f, a3 = 0.f;
    const float* fr = fs + r * 68;
    #pragma unroll
    for (int k = 0; k < 64; ++k) {
        float f = fr[k];
        float4 w = *(const float4*)&Ws[k * 64 + cg * 4];
        a0 = fmaf(f, w.x, a0); a1 = fmaf(f, w.y, a1);
        a2 = fmaf(f, w.z, a2); a3 = fmaf(f, w.w, a3);
    }
    a0 = fmaxf(a0, 0.f); a1 = fmaxf(a1, 0.f);
    a2 = fmaxf(a2, 0.f); a3 = fmaxf(a3, 0.f);
    const int row = r0 + r;
    *(float4*)&out_fea[row * 64 + cg * 4] = make_float4(a0, a1, a2, a3);

    float4 wc = *(const float4*)&Wcls[cg * 4];
    float s = a0*wc.x + a1*wc.y + a2*wc.z + a3*wc.w;
    for (int off = 1; off < 16; off <<= 1) s += __shfl_xor(s, off, 16);
    if (cg == 0) out_pred[row] = s;
}

// K2 (round-11): block 0 = exact radix-256 select; blocks 1..16 bitmask build.
// IDEMPOTENT (atomicOr of same bits; same thres) — launched TWICE this round
// to measure its duration: delta vs the 35.1 us baseline = selscat + 1 boundary.
__global__ __launch_bounds__(1024) void k_selscat(const float* __restrict__ p,
        const int* __restrict__ tc, unsigned int* __restrict__ bmask,
        float* __restrict__ thres_out) {
    __shared__ unsigned int keys[N_PTS];        // 64 KB
    __shared__ unsigned int whist[16][256];     // 16 KB
    __shared__ unsigned int hist[256];
    __shared__ unsigned int scanb[256];
    __shared__ unsigned int sh_prefix, sh_rank;
    const int tid = threadIdx.x;

    if (blockIdx.x != 0) {                      // bitmask build
        const int id = (blockIdx.x - 1) * 1024 + tid;
        int4 c = *(const int4*)&tc[id * 4];
        int key = ((c.x * 64 + c.y) * 64 + c.z) * 64 + c.w;
        atomicOr(&bmask[key >> 5], 1u << (key & 31));
        return;
    }

    const int w = tid >> 6;
    for (int i = tid; i < N_PTS / 4; i += 1024) {
        float4 v = ((const float4*)p)[i];
        keys[i*4 + 0] = mono_key(v.x);
        keys[i*4 + 1] = mono_key(v.y);
        keys[i*4 + 2] = mono_key(v.z);
        keys[i*4 + 3] = mono_key(v.w);
    }
    if (tid == 0) { sh_prefix = 0u; sh_rank = TPN - 1; }
    __syncthreads();

    for (int pass = 0; pass < 4; ++pass) {
        const int shift = 24 - pass * 8;
        const unsigned int prefix = sh_prefix;
        const unsigned int rank = sh_rank;
        for (int t = tid; t < 16 * 256; t += 1024) ((unsigned int*)whist)[t] = 0u;
        __syncthreads();
        for (int i = tid; i < N_PTS; i += 1024) {
            unsigned int u = keys[i];
            bool match = (pass == 0) || ((u >> (shift + 8)) == prefix);
            if (match) atomicAdd(&whist[w][(u >> shift) & 255u], 1u);
        }
        __syncthreads();
        if (tid < 256) {
            unsigned int s = 0u;
            #pragma unroll
            for (int ww = 0; ww < 16; ++ww) s += whist[ww][tid];
            hist[tid] = s;
            scanb[tid] = s;
        }
        __syncthreads();
        for (int d = 1; d < 256; d <<= 1) {
            unsigned int v = 0u;
            if (tid < 256 && tid >= d) v = scanb[tid - d];
            __syncthreads();
            if (tid < 256) scanb[tid] += v;
            __syncthreads();
        }
        if (tid < 256) {
            unsigned int hi = scanb[tid];
            unsigned int lo = hi - hist[tid];
            if (rank >= lo && rank < hi) {
                sh_prefix = (prefix << 8) | (unsigned int)tid;
                sh_rank = rank - lo;
            }
        }
        __syncthreads();
    }
    if (tid == 0) {
        unsigned int u = sh_prefix;
        thres_out[0] = (u & 0x80000000u) ? __uint_as_float(u ^ 0x80000000u)
                                         : __uint_as_float(~u);
    }
}

// K3 (round-11): epilogue with bitmask-probe NN.
__global__ __launch_bounds__(256) void k_final(const int* __restrict__ coords,
        const unsigned int* __restrict__ bmask, const float* __restrict__ thres_p,
        const float* __restrict__ out_pred, float* __restrict__ out_fea,
        float* __restrict__ out_keep, float* __restrict__ out_kt,
        float* __restrict__ out_loss) {
    __shared__ float kscale[64];
    const int tid = threadIdx.x;
    const int r0 = blockIdx.x * 64;
    if (tid < 64) {
        const int i = r0 + tid;
        float p = out_pred[i];
        float thres = thres_p[0];
        int4 c = *(const int4*)&coords[i * 4];
        const int b = c.x, x = c.y, y = c.z, z = c.w;
        int key0 = ((b * 64 + x) * 64 + y) * 64 + z;
        bool kt = (bmask[key0 >> 5] >> (key0 & 31)) & 1u;
        float dists;
        if (kt) {
            dists = 0.f;
        } else {
            dists = 5.f;                     // sentinel > DUB2: "not found"
            int t = 1;
            #pragma unroll
            for (int g = 1; g <= 4; ++g) {
                const int gend = (g == 1) ? 7 : (g == 2) ? 19 : (g == 3) ? 27 : 33;
                bool hit = false;
                for (; t < gend; ++t) {
                    int ox = x + NOFF[t][0], oy = y + NOFF[t][1], oz = z + NOFF[t][2];
                    if (((unsigned)ox | (unsigned)oy | (unsigned)oz) < 64u) {
                        int key = ((b * 64 + ox) * 64 + oy) * 64 + oz;
                        hit |= (bmask[key >> 5] >> (key & 31)) & 1u;
                    }
                }
                if (hit) { dists = (float)g; break; }
            }
        }
        bool keep0 = (p <= thres);
        bool pm = (p > DUB2), tm = (dists > DUB2);
        float loss = (pm && tm) ? p : ((!pm && tm) ? DUB2 : dists);
        bool kf = keep0 || kt;
        out_keep[i] = kf ? 1.f : 0.f;
        out_kt[i]  = kt ? 1.f : 0.f;
        out_loss[i] = loss;
        kscale[tid] = kf ? 1.f : 0.f;
    }
    __syncthreads();
    float4* fbase = (float4*)(out_fea + r0 * 64);
    #pragma unroll
    for (int q = 0; q < 4; ++q) {
        int v = tid + q * 256;               // 64 rows x 16 float4 = 1024
        float sc = kscale[v >> 4];
        float4 xv = fbase[v];
        xv.x *= sc; xv.y *= sc; xv.z *= sc; xv.w *= sc;
        fbase[v] = xv;
    }
}

extern "C" void kernel_launch(void* const* d_in, const int* in_sizes, int n_in,
                              void* d_out, int out_size, void* d_ws, size_t ws_size,
                              hipStream_t stream) {
    const float* fea     = (const float*)d_in[0];
    const float* Wup     = (const float*)d_in[1];
    const float* Wcls    = (const float*)d_in[2];
    const int*   coords  = (const int*)d_in[3];
    const int*   tcoords = (const int*)d_in[4];

    float* out      = (float*)d_out;
    float* out_pred = out;
    float* out_fea  = out + N_PTS;
    float* out_keep = out + N_PTS + N_PTS * 64;
    float* out_kt   = out_keep + N_PTS;
    float* out_loss = out_kt + N_PTS;

    char* ws = (char*)d_ws;
    unsigned int* bmask   = (unsigned int*)(ws + 64);          // 128 KB -> 131136
    float*        thres   = (float*)(ws + 131136);             // 4 B

    k_gemm   <<<N_PTS / 16, 256, 0, stream>>>(fea, Wup, Wcls, out_pred, out_fea, bmask);
    // MEASUREMENT: selscat launched twice (idempotent) — delta vs 35.1 us
    // baseline = one selscat duration + one dispatch boundary.
    k_selscat<<<1 + M_TGT / 1024, 1024, 0, stream>>>(out_pred, tcoords, bmask, thres);
    k_selscat<<<1 + M_TGT / 1024, 1024, 0, stream>>>(out_pred, tcoords, bmask, thres);
    k_final  <<<N_PTS / 64, 256, 0, stream>>>(coords, bmask, thres,
                                              out_pred, out_fea, out_keep, out_kt, out_loss);
}